// Round 1
// baseline (1423.820 us; speedup 1.0000x reference)
//
#include <hip/hip_runtime.h>
#include <math.h>
#include <stdint.h>

typedef unsigned short u16;
typedef __attribute__((ext_vector_type(8))) short short8;
typedef __attribute__((ext_vector_type(4))) float f32x4;

#define B_   4
#define S_   2048
#define D_   4096
#define H_   32
#define KVH_ 8
#define HD_  128
#define NQKV 6144
#define MTOT 8192
#define ATT_SCALE 0.08838834764831845f

__device__ __forceinline__ float bf2f(u16 u) {
  unsigned x = ((unsigned)u) << 16;
  return __builtin_bit_cast(float, x);
}
__device__ __forceinline__ u16 f2bf(float f) {
  unsigned x = __builtin_bit_cast(unsigned, f);
  x += 0x7fffu + ((x >> 16) & 1u);
  return (u16)(x >> 16);
}

// swizzled element index for LDS tiles with 64-element (128B) rows, chunk=8 elems
__device__ __forceinline__ int swz64(int row, int kc) {
  return row * 64 + ((kc ^ (row & 7)) << 3);
}
// 128-element (256B) rows, kc 0..15
__device__ __forceinline__ int swz128(int row, int kc) {
  return row * 128 + ((kc ^ (row & 7)) << 3);
}

// ---------------- cast x (f32 -> bf16) ----------------
__global__ void cast_f32_to_bf16(const float* __restrict__ in, u16* __restrict__ out, long n) {
  long i = ((long)blockIdx.x * 256 + threadIdx.x) * 4;
  if (i >= n) return;
  float4 v = *(const float4*)(in + i);
  ushort4 o;
  o.x = f2bf(v.x); o.y = f2bf(v.y); o.z = f2bf(v.z); o.w = f2bf(v.w);
  *(ushort4*)(out + i) = o;
}

// ---------------- transpose+cast weight: f32 [K][N] -> bf16 [N][K] ----------------
__global__ void transpose_cast(const float* __restrict__ in, u16* __restrict__ out, int K, int N) {
  __shared__ u16 tile[32][33];
  int n0 = blockIdx.x * 32, k0 = blockIdx.y * 32;
  int tx = threadIdx.x, ty = threadIdx.y;
  for (int i = ty; i < 32; i += 8)
    tile[i][tx] = f2bf(in[(long)(k0 + i) * N + n0 + tx]);
  __syncthreads();
  for (int i = ty; i < 32; i += 8)
    out[(long)(n0 + i) * K + k0 + tx] = tile[tx][i];
}

// ---------------- GEMM: C[M][N] = A[M][K] * BT[N][K]^T  (bf16 in, f32 acc) ------
template <int OUTF32>
__global__ __launch_bounds__(256) void gemm_bt(const u16* __restrict__ A,
                                               const u16* __restrict__ BT,
                                               void* __restrict__ Cout,
                                               int M, int N, int K) {
  __shared__ u16 As[128 * 64];
  __shared__ u16 Bs[128 * 64];
  int tid = threadIdx.x;
  int lane = tid & 63, wid = tid >> 6;
  int wm = wid >> 1, wn = wid & 1;
  int m0 = blockIdx.y * 128, n0 = blockIdx.x * 128;

  int srow = tid >> 3;   // 0..31
  int skc = tid & 7;     // 0..7
  const u16* ag = A + (long)(m0 + srow) * K + skc * 8;
  const u16* bg = BT + (long)(n0 + srow) * K + skc * 8;

  int frow = lane & 15;
  int fk = lane >> 4;

  f32x4 acc[4][4];
#pragma unroll
  for (int i = 0; i < 4; i++)
#pragma unroll
    for (int j = 0; j < 4; j++) acc[i][j] = (f32x4){0.f, 0.f, 0.f, 0.f};

  short8 ra[4], rb[4];
#pragma unroll
  for (int i = 0; i < 4; i++) {
    ra[i] = *(const short8*)(ag + (long)(i * 32) * K);
    rb[i] = *(const short8*)(bg + (long)(i * 32) * K);
  }

  int nk = K / 64;
  for (int t = 0; t < nk; ++t) {
#pragma unroll
    for (int i = 0; i < 4; i++) {
      *(short8*)&As[swz64(i * 32 + srow, skc)] = ra[i];
      *(short8*)&Bs[swz64(i * 32 + srow, skc)] = rb[i];
    }
    __syncthreads();
    if (t + 1 < nk) {
      const u16* ag2 = ag + (t + 1) * 64;
      const u16* bg2 = bg + (t + 1) * 64;
#pragma unroll
      for (int i = 0; i < 4; i++) {
        ra[i] = *(const short8*)(ag2 + (long)(i * 32) * K);
        rb[i] = *(const short8*)(bg2 + (long)(i * 32) * K);
      }
    }
#pragma unroll
    for (int kk = 0; kk < 2; ++kk) {
      short8 af[4], bfr[4];
#pragma unroll
      for (int i = 0; i < 4; i++)
        af[i] = *(const short8*)&As[swz64(wm * 64 + i * 16 + frow, kk * 4 + fk)];
#pragma unroll
      for (int j = 0; j < 4; j++)
        bfr[j] = *(const short8*)&Bs[swz64(wn * 64 + j * 16 + frow, kk * 4 + fk)];
#pragma unroll
      for (int i = 0; i < 4; i++)
#pragma unroll
        for (int j = 0; j < 4; j++)
          acc[i][j] = __builtin_amdgcn_mfma_f32_16x16x32_bf16(af[i], bfr[j], acc[i][j], 0, 0, 0);
    }
    __syncthreads();
  }

  // epilogue: C/D layout col=lane&15, row=(lane>>4)*4+reg
  int cc = lane & 15, cr = (lane >> 4) * 4;
#pragma unroll
  for (int i = 0; i < 4; i++)
#pragma unroll
    for (int j = 0; j < 4; j++) {
#pragma unroll
      for (int r = 0; r < 4; r++) {
        int m = m0 + wm * 64 + i * 16 + cr + r;
        int n = n0 + wn * 64 + j * 16 + cc;
        if (OUTF32)
          ((float*)Cout)[(long)m * N + n] = acc[i][j][r];
        else
          ((u16*)Cout)[(long)m * N + n] = f2bf(acc[i][j][r]);
      }
    }
}

// ---------------- RoPE in-place on qkv buffer (Q and K columns) ----------------
__global__ void rope_kernel(u16* __restrict__ qkv, const float* __restrict__ cosb,
                            const float* __restrict__ sinb, const int* __restrict__ start_pos) {
  long tid = (long)blockIdx.x * 256 + threadIdx.x;
  const long total = (long)MTOT * 2560;  // 2048 Q pairs + 512 K pairs per row
  if (tid >= total) return;
  int row = (int)(tid / 2560);
  int p = (int)(tid % 2560);
  int col = (p < 2048) ? (p * 2) : (D_ + (p - 2048) * 2);
  int i = (col >> 1) & 63;
  int s = row & (S_ - 1);
  int pos = s + *start_pos;
  float c = cosb[pos * 64 + i];
  float sn = sinb[pos * 64 + i];
  u16* ptr = qkv + (long)row * NQKV + col;
  unsigned v = *(unsigned*)ptr;
  float x0 = bf2f((u16)(v & 0xffff));
  float x1 = bf2f((u16)(v >> 16));
  float o0 = x0 * c - x1 * sn;
  float o1 = x0 * sn + x1 * c;
  unsigned ov = (unsigned)f2bf(o0) | ((unsigned)f2bf(o1) << 16);
  *(unsigned*)ptr = ov;
}

// ---------------- build VT[b][kvh][d=128][s=2048] from qkv V columns ----------------
__global__ void build_vt(const u16* __restrict__ qkv, u16* __restrict__ vt) {
  int bk = blockIdx.z;
  int b = bk >> 3, kvh = bk & 7;
  int s0 = blockIdx.x * 32, d0 = blockIdx.y * 32;
  __shared__ u16 tile[32][33];
  int tx = threadIdx.x, ty = threadIdx.y;
  const u16* src = qkv + (long)(b * S_) * NQKV + D_ + KVH_ * HD_ + kvh * HD_;
  for (int i = ty; i < 32; i += 8)
    tile[i][tx] = src[(long)(s0 + i) * NQKV + d0 + tx];
  __syncthreads();
  u16* dst = vt + ((long)(b * KVH_ + kvh) * HD_) * S_;
  for (int i = ty; i < 32; i += 8)
    dst[(long)(d0 + i) * S_ + s0 + tx] = tile[tx][i];
}

// ---------------- flash attention (non-causal, GQA) ----------------
__global__ __launch_bounds__(256) void attn_kernel(const u16* __restrict__ qkv,
                                                   const u16* __restrict__ vt,
                                                   u16* __restrict__ obuf) {
  int bh = blockIdx.y;
  int b = bh >> 5, h = bh & 31;
  int kvh = h >> 2;
  int q0 = blockIdx.x * 64;
  int tid = threadIdx.x, lane = tid & 63, wid = tid >> 6;

  __shared__ u16 Ks[64 * 128];    // [kv][d], swizzled 256B rows
  __shared__ u16 VTs[128 * 64];   // [d][kv], swizzled 128B rows
  __shared__ u16 Ps[4][16 * 64];  // per-wave P [q][kv], swizzled

  int frow = lane & 15;
  int fk = lane >> 4;

  // Q fragments (A-layout: row=lane&15, k=8*(lane>>4)+j), 4 chunks over d=128
  const u16* qbase = qkv + (long)(b * S_ + q0 + wid * 16 + frow) * NQKV + h * HD_;
  short8 qf[4];
#pragma unroll
  for (int kd = 0; kd < 4; ++kd) qf[kd] = *(const short8*)(qbase + kd * 32 + fk * 8);

  f32x4 acc_o[8];
#pragma unroll
  for (int i = 0; i < 8; i++) acc_o[i] = (f32x4){0.f, 0.f, 0.f, 0.f};
  float m_r[4] = {-1e30f, -1e30f, -1e30f, -1e30f};
  float l_r[4] = {0.f, 0.f, 0.f, 0.f};

  // staging indices
  int krow = tid >> 4, kkc = tid & 15;  // K tile: 16 chunks/row
  int vrow = tid >> 3, vkc = tid & 7;   // VT tile: 8 chunks/row
  const u16* kg = qkv + (long)(b * S_ + krow) * NQKV + D_ + kvh * HD_ + kkc * 8;
  const u16* vg = vt + ((long)(b * KVH_ + kvh) * HD_ + vrow) * S_ + vkc * 8;

  short8 rk[4], rv[4];
#pragma unroll
  for (int i = 0; i < 4; i++) {
    rk[i] = *(const short8*)(kg + (long)(i * 16) * NQKV);
    rv[i] = *(const short8*)(vg + (long)(i * 32) * S_);
  }

  const int ntiles = S_ / 64;
  for (int t = 0; t < ntiles; ++t) {
#pragma unroll
    for (int i = 0; i < 4; i++) {
      *(short8*)&Ks[swz128(i * 16 + krow, kkc)] = rk[i];
      *(short8*)&VTs[swz64(i * 32 + vrow, vkc)] = rv[i];
    }
    __syncthreads();
    if (t + 1 < ntiles) {
      const u16* kg2 = kg + (long)(t + 1) * 64 * NQKV;
      const u16* vg2 = vg + (t + 1) * 64;
#pragma unroll
      for (int i = 0; i < 4; i++) {
        rk[i] = *(const short8*)(kg2 + (long)(i * 16) * NQKV);
        rv[i] = *(const short8*)(vg2 + (long)(i * 32) * S_);
      }
    }

    // QK^T: scores 16x64 per wave
    f32x4 sc[4];
#pragma unroll
    for (int f = 0; f < 4; f++) sc[f] = (f32x4){0.f, 0.f, 0.f, 0.f};
#pragma unroll
    for (int f = 0; f < 4; f++)
#pragma unroll
      for (int kd = 0; kd < 4; kd++) {
        short8 kf = *(const short8*)&Ks[swz128(f * 16 + frow, kd * 4 + fk)];
        sc[f] = __builtin_amdgcn_mfma_f32_16x16x32_bf16(qf[kd], kf, sc[f], 0, 0, 0);
      }

    // online softmax (rows q = fk*4+r, cols kv = f*16+frow)
    float mnew[4], scl[4], rs[4];
#pragma unroll
    for (int r = 0; r < 4; r++) {
#pragma unroll
      for (int f = 0; f < 4; f++) sc[f][r] *= ATT_SCALE;
      float tm = fmaxf(fmaxf(sc[0][r], sc[1][r]), fmaxf(sc[2][r], sc[3][r]));
#pragma unroll
      for (int off = 1; off < 16; off <<= 1) tm = fmaxf(tm, __shfl_xor(tm, off, 64));
      mnew[r] = fmaxf(m_r[r], tm);
      scl[r] = __expf(m_r[r] - mnew[r]);
      rs[r] = 0.f;
#pragma unroll
      for (int f = 0; f < 4; f++) {
        float pv = __expf(sc[f][r] - mnew[r]);
        rs[r] += pv;
        int q = fk * 4 + r;
        int kv = f * 16 + frow;
        Ps[wid][q * 64 + (((kv >> 3) ^ (q & 7)) << 3) + (kv & 7)] = f2bf(pv);
      }
#pragma unroll
      for (int off = 1; off < 16; off <<= 1) rs[r] += __shfl_xor(rs[r], off, 64);
      l_r[r] = l_r[r] * scl[r] + rs[r];
      m_r[r] = mnew[r];
    }
#pragma unroll
    for (int df = 0; df < 8; df++)
#pragma unroll
      for (int r = 0; r < 4; r++) acc_o[df][r] *= scl[r];

    asm volatile("s_waitcnt lgkmcnt(0)" ::: "memory");

    // PV: A = P (q x kv), B^T = VT (d x kv)
    short8 pf[2];
#pragma unroll
    for (int kk = 0; kk < 2; kk++)
      pf[kk] = *(const short8*)&Ps[wid][swz64(frow, kk * 4 + fk)];
#pragma unroll
    for (int df = 0; df < 8; df++)
#pragma unroll
      for (int kk = 0; kk < 2; kk++) {
        short8 vf = *(const short8*)&VTs[swz64(df * 16 + frow, kk * 4 + fk)];
        acc_o[df] = __builtin_amdgcn_mfma_f32_16x16x32_bf16(pf[kk], vf, acc_o[df], 0, 0, 0);
      }
    __syncthreads();
  }

  // epilogue: O /= l, write bf16 [b][s][h*128+d]
#pragma unroll
  for (int r = 0; r < 4; r++) {
    float inv = 1.0f / l_r[r];
    int q = fk * 4 + r;
#pragma unroll
    for (int df = 0; df < 8; df++) {
      int d = df * 16 + frow;
      obuf[(long)(b * S_ + q0 + wid * 16 + q) * D_ + h * HD_ + d] = f2bf(acc_o[df][r] * inv);
    }
  }
}

// ---------------- launch ----------------
extern "C" void kernel_launch(void* const* d_in, const int* in_sizes, int n_in,
                              void* d_out, int out_size, void* d_ws, size_t ws_size,
                              hipStream_t stream) {
  const float* x = (const float*)d_in[0];
  const float* wq = (const float*)d_in[1];
  const float* wk = (const float*)d_in[2];
  const float* wv = (const float*)d_in[3];
  const float* wo = (const float*)d_in[4];
  const float* cosb = (const float*)d_in[5];
  const float* sinb = (const float*)d_in[6];
  const int* start_pos = (const int*)d_in[9];
  float* out = (float*)d_out;

  char* ws = (char*)d_ws;
  u16* xb = (u16*)ws;                                   // [8192][4096] bf16: 67108864 B
  u16* wqkvT = (u16*)(ws + 67108864L);                  // [6144][4096] bf16: 50331648 B
  u16* woT = (u16*)(ws + 117440512L);                   // [4096][4096] bf16: 33554432 B
  u16* qkvb = (u16*)(ws + 150994944L);                  // [8192][6144] bf16: 100663296 B
  u16* vtb = (u16*)(ws + 251658240L);                   // [4][8][128][2048] bf16: 16777216 B
  u16* obuf = xb;                                       // reuse xb after GEMM1

  // 1. cast x
  cast_f32_to_bf16<<<dim3(32768), dim3(256), 0, stream>>>(x, xb, (long)MTOT * D_);

  // 2. transpose-cast weights into B^T layout
  transpose_cast<<<dim3(128, 128), dim3(32, 8), 0, stream>>>(wq, wqkvT, D_, 4096);
  transpose_cast<<<dim3(32, 128), dim3(32, 8), 0, stream>>>(wk, wqkvT + (long)4096 * D_, D_, 1024);
  transpose_cast<<<dim3(32, 128), dim3(32, 8), 0, stream>>>(wv, wqkvT + (long)5120 * D_, D_, 1024);
  transpose_cast<<<dim3(128, 128), dim3(32, 8), 0, stream>>>(wo, woT, D_, 4096);

  // 3. QKV GEMM: [8192][6144] = xb * wqkvT^T
  gemm_bt<0><<<dim3(NQKV / 128, MTOT / 128), dim3(256), 0, stream>>>(xb, wqkvT, qkvb, MTOT, NQKV, D_);

  // 4. RoPE in-place on Q,K
  rope_kernel<<<dim3(81920), dim3(256), 0, stream>>>(qkvb, cosb, sinb, start_pos);

  // 5. V transpose
  build_vt<<<dim3(64, 4, 32), dim3(32, 8), 0, stream>>>(qkvb, vtb);

  // 6. attention
  attn_kernel<<<dim3(S_ / 64, B_ * H_), dim3(256), 0, stream>>>(qkvb, vtb, obuf);

  // 7. output GEMM: out f32 = obuf * woT^T
  gemm_bt<1><<<dim3(D_ / 128, MTOT / 128), dim3(256), 0, stream>>>(obuf, woT, out, MTOT, D_, D_);
}